// Round 7
// baseline (178.783 us; speedup 1.0000x reference)
//
#include <hip/hip_runtime.h>
#include <hip/hip_bf16.h>

#define BB   128
#define CIN  9
#define TT   2048
#define RR   512
#define NN   (BB*RR)     // 65536
#define HID  128
#define NOUT 12

typedef __attribute__((ext_vector_type(8))) short short8;
typedef __attribute__((ext_vector_type(4))) float f32x4;

static __device__ inline unsigned short f2bf(float f) {       // RNE f32->bf16
    unsigned int u = __float_as_uint(f);
    unsigned int r = (u + 0x7fffu + ((u >> 16) & 1u)) >> 16;
    return (unsigned short)r;
}
static __device__ inline float bf2f(unsigned short u) {
    return __uint_as_float(((unsigned int)u) << 16);
}

// =======================================================================
// Fused conv1+relu+pool2 -> conv2+relu+pool2  (blocks 0..1023, 64 nodes each)
// block 1024: per-sample CSR build; block 1025: W1^T/W2^T -> bf16
// =======================================================================
__global__ __launch_bounds__(512) void k_convs(const float* __restrict__ x,
        const float* __restrict__ w1, const float* __restrict__ b1,
        const float* __restrict__ w2, const float* __restrict__ b2,
        float* __restrict__ nodes,
        const int* __restrict__ ei, int E, int es,
        int* __restrict__ rptr, float* __restrict__ dis, int* __restrict__ adj,
        const float* __restrict__ g1w, const float* __restrict__ g2w,
        unsigned short* __restrict__ w1t, unsigned short* __restrict__ w2t) {
    __shared__ float sx[CIN][268];     // x tile
    __shared__ float s1[16][132];      // pooled conv1
    __shared__ int lcnt[512];
    __shared__ int sp[512];
    __shared__ int lcur[512];
    int tid = threadIdx.x;

    if (blockIdx.x == 1024) {
        // ---- CSR build for the per-sample graph ----
        int t = tid;
        lcnt[t] = 0;
        __syncthreads();
        for (int i = t; i < es; i += 512) atomicAdd(&lcnt[ei[E + i]], 1);
        __syncthreads();
        int c = lcnt[t];
        sp[t] = c;
        __syncthreads();
        for (int off = 1; off < 512; off <<= 1) {
            int v = sp[t];
            int add = (t >= off) ? sp[t - off] : 0;
            __syncthreads();
            sp[t] = v + add;
            __syncthreads();
        }
        int excl = sp[t] - c;
        rptr[t] = excl;
        if (t == 511) rptr[512] = es;
        dis[t] = rsqrtf((float)c + 1.0f);
        lcur[t] = excl;
        __syncthreads();
        for (int i = t; i < es; i += 512) {
            int row = ei[i], col = ei[E + i];
            int pos = atomicAdd(&lcur[col], 1);
            adj[pos] = row;
        }
        return;
    }
    if (blockIdx.x == 1025) {
        // ---- transpose + bf16-cast GCN weights ----
        for (int idx = tid; idx < 32 * 128; idx += 512) {
            int c = idx >> 7, f = idx & 127;
            w1t[f * 32 + c] = f2bf(g1w[idx]);
        }
        for (int idx = tid; idx < 128 * 128; idx += 512) {
            int c = idx >> 7, f = idx & 127;
            w2t[f * 128 + c] = f2bf(g2w[idx]);
        }
        return;
    }

    int b  = blockIdx.x >> 3;
    int r0 = (blockIdx.x & 7) * 64;
    int wv   = __builtin_amdgcn_readfirstlane(tid >> 6);   // wave 0..7
    int lane = tid & 63;

    for (int idx = tid; idx < CIN * 268; idx += 512) {
        int c = idx / 268, j = idx - c * 268;
        int g = 4 * r0 - 6 + j;
        float v = 0.f;
        if (g >= 0 && g < TT) v = x[(b * CIN + c) * TT + g];
        sx[c][j] = v;
    }
    __syncthreads();

#pragma unroll
    for (int cc = 0; cc < 2; ++cc) {
        int c1 = wv * 2 + cc;
        float bias1 = b1[c1];
        for (int pp = lane; pp < 132; pp += 64) {
            int p = 2 * r0 - 2 + pp;
            float val = 0.f;
            if (p >= 0 && p < 1024) {
                float a0 = bias1, a1 = bias1;
#pragma unroll
                for (int c = 0; c < CIN; ++c) {
                    const float2* px = (const float2*)&sx[c][2 * pp];
                    float2 q0 = px[0], q1 = px[1], q2 = px[2];
                    const float* wp = &w1[(c1 * CIN + c) * 5];
                    float k0 = wp[0], k1 = wp[1], k2 = wp[2], k3 = wp[3], k4 = wp[4];
                    a0 += q0.x*k0 + q0.y*k1 + q1.x*k2 + q1.y*k3 + q2.x*k4;
                    a1 += q0.y*k0 + q1.x*k1 + q1.y*k2 + q2.x*k3 + q2.y*k4;
                }
                val = fmaxf(fmaxf(a0, a1), 0.f);
            }
            s1[c1][pp] = val;
        }
    }
    __syncthreads();

    int rl = lane;
    float acc0[4], acc1[4];
#pragma unroll
    for (int o = 0; o < 4; ++o) {
        float bv = b2[wv * 4 + o];
        acc0[o] = bv; acc1[o] = bv;
    }
#pragma unroll
    for (int c = 0; c < 16; ++c) {
        const float2* ps = (const float2*)&s1[c][2 * rl];
        float2 q0 = ps[0], q1 = ps[1], q2 = ps[2];
#pragma unroll
        for (int o = 0; o < 4; ++o) {
            const float* wp = &w2[((wv * 4 + o) * 16 + c) * 5];
            float k0 = wp[0], k1 = wp[1], k2 = wp[2], k3 = wp[3], k4 = wp[4];
            acc0[o] += q0.x*k0 + q0.y*k1 + q1.x*k2 + q1.y*k3 + q2.x*k4;
            acc1[o] += q0.y*k0 + q1.x*k1 + q1.y*k2 + q2.x*k3 + q2.y*k4;
        }
    }
    int n = b * RR + r0 + rl;
    float4 ov;
    ov.x = fmaxf(fmaxf(acc0[0], acc1[0]), 0.f);
    ov.y = fmaxf(fmaxf(acc0[1], acc1[1]), 0.f);
    ov.z = fmaxf(fmaxf(acc0[2], acc1[2]), 0.f);
    ov.w = fmaxf(fmaxf(acc0[3], acc1[3]), 0.f);
    *(float4*)&nodes[n * 32 + wv * 4] = ov;
}

// =======================================================================
// Layer 1: LDS-resident sample window; gather32 from LDS; lin1 via MFMA.
// 2 blocks/sample (halves of 256 nodes), 512 threads.
// LDS: snode[512][36] f32 (72K) + srow[256][40] bf16 (20K) + sdis (2K)
// =======================================================================
__global__ __launch_bounds__(512, 2) void k_gl1(const int* __restrict__ rptr,
        const int* __restrict__ adj, const float* __restrict__ dis,
        const float* __restrict__ nodes, const unsigned short* __restrict__ w1t,
        const float* __restrict__ bias, unsigned short* __restrict__ h16) {
    __shared__ float snode[512][36];
    __shared__ unsigned short srow[256][40];
    __shared__ float sdis[512];
    int tid = threadIdx.x;
    int vb = blockIdx.x;
    int xcd = vb & 7, slot = vb >> 3;
    int b = xcd * 16 + (slot >> 1);
    int half = slot & 1;

    {   // stage sample window: 512x32 f32
        const float4* src = (const float4*)(nodes + (size_t)b * RR * 32);
#pragma unroll
        for (int i = 0; i < 32; ++i) {
            int idx = tid + i * 512;          // float4 idx, 16384 total
            int row = idx >> 3, c4 = idx & 7;
            *(float4*)&snode[row][c4 * 4] = src[idx];
        }
        if (tid < 512) sdis[tid] = dis[tid];
    }
    __syncthreads();

    // gather phase: 64 nodes at a time (8 lanes/node), 4 iterations
    int lane8 = tid & 7;
    int gidx  = tid >> 3;        // 0..63
#pragma unroll
    for (int nlg = 0; nlg < 4; ++nlg) {
        int nl = nlg * 64 + gidx;            // local node 0..255
        int r  = half * 256 + nl;            // node in sample
        int s = rptr[r], e = rptr[r + 1];
        float dn = sdis[r];
        float4 acc = make_float4(0.f, 0.f, 0.f, 0.f);
        for (int base = s; base < e; base += 8) {
            int j = base + lane8;
            int src = 0; float nd = 0.f;
            if (j < e) { src = adj[j]; nd = sdis[src]; }
            int cnt = min(8, e - base);
            int k = 0;
            for (; k + 4 <= cnt; k += 4) {
                int   s0 = __shfl(src, k, 8),     s1 = __shfl(src, k + 1, 8);
                int   s2 = __shfl(src, k + 2, 8), s3 = __shfl(src, k + 3, 8);
                float n0 = __shfl(nd, k, 8),      n1 = __shfl(nd, k + 1, 8);
                float n2 = __shfl(nd, k + 2, 8),  n3 = __shfl(nd, k + 3, 8);
                float4 v0 = *(const float4*)&snode[s0][lane8 * 4];
                float4 v1 = *(const float4*)&snode[s1][lane8 * 4];
                float4 v2 = *(const float4*)&snode[s2][lane8 * 4];
                float4 v3 = *(const float4*)&snode[s3][lane8 * 4];
                float w0 = dn * n0, w1 = dn * n1, w2 = dn * n2, w3 = dn * n3;
                acc.x += w0*v0.x + w1*v1.x + w2*v2.x + w3*v3.x;
                acc.y += w0*v0.y + w1*v1.y + w2*v2.y + w3*v3.y;
                acc.z += w0*v0.z + w1*v1.z + w2*v2.z + w3*v3.z;
                acc.w += w0*v0.w + w1*v1.w + w2*v2.w + w3*v3.w;
            }
            for (; k < cnt; ++k) {
                int   sk = __shfl(src, k, 8);
                float nk = __shfl(nd, k, 8);
                float4 v = *(const float4*)&snode[sk][lane8 * 4];
                float wgt = dn * nk;
                acc.x += wgt * v.x; acc.y += wgt * v.y;
                acc.z += wgt * v.z; acc.w += wgt * v.w;
            }
        }
        {   // self loop
            float4 v = *(const float4*)&snode[r][lane8 * 4];
            float wgt = dn * dn;
            acc.x += wgt * v.x; acc.y += wgt * v.y;
            acc.z += wgt * v.z; acc.w += wgt * v.w;
        }
        ushort4 o;
        o.x = f2bf(acc.x); o.y = f2bf(acc.y); o.z = f2bf(acc.z); o.w = f2bf(acc.w);
        *(ushort4*)&srow[nl][lane8 * 4] = o;
    }
    __syncthreads();

    // lin1 MFMA: srow[256x32]bf16 @ W1[32x128] -> relu(+bias) -> h16
    int wv   = tid >> 6;          // wave 0..7: rows wv*32..wv*32+31
    int lane = tid & 63;
    int l15  = lane & 15;
    int quad = lane >> 4;
    short8 bfr[8];
#pragma unroll
    for (int nt = 0; nt < 8; ++nt)
        bfr[nt] = *(const short8*)&w1t[(nt * 16 + l15) * 32 + quad * 8];
    float bcol[8];
#pragma unroll
    for (int nt = 0; nt < 8; ++nt) bcol[nt] = bias[nt * 16 + l15];
#pragma unroll
    for (int t = 0; t < 2; ++t) {
        int m0 = wv * 32 + t * 16;
        short8 a = *(const short8*)&srow[m0 + l15][quad * 8];
        f32x4 acc[8];
#pragma unroll
        for (int nt = 0; nt < 8; ++nt) {
            acc[nt] = (f32x4){0.f, 0.f, 0.f, 0.f};
            acc[nt] = __builtin_amdgcn_mfma_f32_16x16x32_bf16(a, bfr[nt], acc[nt], 0, 0, 0);
        }
#pragma unroll
        for (int nt = 0; nt < 8; ++nt) {
            int col = nt * 16 + l15;
#pragma unroll
            for (int rr2 = 0; rr2 < 4; ++rr2) {
                int node = b * RR + half * 256 + m0 + quad * 4 + rr2;
                h16[(size_t)node * 128 + col] = f2bf(fmaxf(acc[nt][rr2] + bcol[nt], 0.f));
            }
        }
    }
}

// =======================================================================
// Layer 2 megakernel: stage h1 window (bf16) -> lin2 MFMA in-place in LDS
// -> gather+bias+relu from LDS -> per-block mean partials.
// 2 blocks/sample, 512 threads. LDS: hwin[512][136]bf16 (136K) + sgrp (8K)
// =======================================================================
__global__ __launch_bounds__(512, 2) void k_l2(const int* __restrict__ rptr,
        const int* __restrict__ adj, const float* __restrict__ dis,
        const unsigned short* __restrict__ h1, const unsigned short* __restrict__ w2t,
        const float* __restrict__ bias, float* __restrict__ partial) {
    __shared__ unsigned short hwin[512][136];
    __shared__ float sgrp[16][128];
    __shared__ float sdis[512];
    int tid = threadIdx.x;
    int vb = blockIdx.x;
    int xcd = vb & 7, slot = vb >> 3;
    int b = xcd * 16 + (slot >> 1);
    int half = slot & 1;

    {   // stage h1 sample window: 512x128 bf16
        const ushort4* src = (const ushort4*)(h1 + (size_t)b * RR * 128);
#pragma unroll
        for (int i = 0; i < 32; ++i) {
            int idx = tid + i * 512;         // ushort4 idx, 16384 total
            int row = idx >> 5, c4 = idx & 31;
            *(ushort4*)&hwin[row][c4 * 4] = src[idx];
        }
        if (tid < 512) sdis[tid] = dis[tid];
    }
    __syncthreads();

    // ---- lin2 in-place: wave w owns rows [w*64, w*64+64) (row-local) ----
    int wv   = tid >> 6;
    int lane = tid & 63;
    int l15  = lane & 15;
    int quad = lane >> 4;
    short8 bfr[8][4];
#pragma unroll
    for (int nt = 0; nt < 8; ++nt)
#pragma unroll
        for (int kc = 0; kc < 4; ++kc)
            bfr[nt][kc] = *(const short8*)&w2t[(nt * 16 + l15) * 128 + kc * 32 + quad * 8];
#pragma unroll
    for (int mt = 0; mt < 4; ++mt) {
        int m0 = wv * 64 + mt * 16;
        short8 a[4];
#pragma unroll
        for (int kc = 0; kc < 4; ++kc)
            a[kc] = *(const short8*)&hwin[m0 + l15][kc * 32 + quad * 8];
        f32x4 acc[8];
#pragma unroll
        for (int nt = 0; nt < 8; ++nt) acc[nt] = (f32x4){0.f, 0.f, 0.f, 0.f};
#pragma unroll
        for (int kc = 0; kc < 4; ++kc)
#pragma unroll
            for (int nt = 0; nt < 8; ++nt)
                acc[nt] = __builtin_amdgcn_mfma_f32_16x16x32_bf16(a[kc], bfr[nt][kc], acc[nt], 0, 0, 0);
        // write h2 back into the same rows (reads above already completed)
#pragma unroll
        for (int nt = 0; nt < 8; ++nt)
#pragma unroll
            for (int rr2 = 0; rr2 < 4; ++rr2)
                hwin[m0 + quad * 4 + rr2][nt * 16 + l15] = f2bf(acc[nt][rr2]);
    }
    __syncthreads();

    // ---- gather from LDS + self-loop + bias + relu + column partial sums ---
    int grp   = tid >> 5;        // 0..15
    int lane32 = tid & 31;
    float4 bv = *(const float4*)&bias[lane32 * 4];
    float4 csum = make_float4(0.f, 0.f, 0.f, 0.f);
    for (int ni = 0; ni < 16; ++ni) {
        int r = half * 256 + grp * 16 + ni;   // node in sample
        int s = rptr[r], e = rptr[r + 1];
        float dn = sdis[r];
        float4 acc = make_float4(0.f, 0.f, 0.f, 0.f);
        for (int base = s; base < e; base += 32) {
            int j = base + lane32;
            int src = 0; float nd = 0.f;
            if (j < e) { src = adj[j]; nd = sdis[src]; }
            int cnt = min(32, e - base);
            int k = 0;
            for (; k + 4 <= cnt; k += 4) {
                int   s0 = __shfl(src, k, 32),     s1 = __shfl(src, k + 1, 32);
                int   s2 = __shfl(src, k + 2, 32), s3 = __shfl(src, k + 3, 32);
                float n0 = __shfl(nd, k, 32),      n1 = __shfl(nd, k + 1, 32);
                float n2 = __shfl(nd, k + 2, 32),  n3 = __shfl(nd, k + 3, 32);
                ushort4 u0 = *(const ushort4*)&hwin[s0][lane32 * 4];
                ushort4 u1 = *(const ushort4*)&hwin[s1][lane32 * 4];
                ushort4 u2 = *(const ushort4*)&hwin[s2][lane32 * 4];
                ushort4 u3 = *(const ushort4*)&hwin[s3][lane32 * 4];
                float w0 = dn * n0, w1 = dn * n1, w2 = dn * n2, w3 = dn * n3;
                acc.x += w0*bf2f(u0.x) + w1*bf2f(u1.x) + w2*bf2f(u2.x) + w3*bf2f(u3.x);
                acc.y += w0*bf2f(u0.y) + w1*bf2f(u1.y) + w2*bf2f(u2.y) + w3*bf2f(u3.y);
                acc.z += w0*bf2f(u0.z) + w1*bf2f(u1.z) + w2*bf2f(u2.z) + w3*bf2f(u3.z);
                acc.w += w0*bf2f(u0.w) + w1*bf2f(u1.w) + w2*bf2f(u2.w) + w3*bf2f(u3.w);
            }
            for (; k < cnt; ++k) {
                int   sk = __shfl(src, k, 32);
                float nk = __shfl(nd, k, 32);
                ushort4 u = *(const ushort4*)&hwin[sk][lane32 * 4];
                float wgt = dn * nk;
                acc.x += wgt * bf2f(u.x); acc.y += wgt * bf2f(u.y);
                acc.z += wgt * bf2f(u.z); acc.w += wgt * bf2f(u.w);
            }
        }
        ushort4 u = *(const ushort4*)&hwin[r][lane32 * 4];
        float wgt = dn * dn;
        csum.x += fmaxf(acc.x + wgt * bf2f(u.x) + bv.x, 0.f);
        csum.y += fmaxf(acc.y + wgt * bf2f(u.y) + bv.y, 0.f);
        csum.z += fmaxf(acc.z + wgt * bf2f(u.z) + bv.z, 0.f);
        csum.w += fmaxf(acc.w + wgt * bf2f(u.w) + bv.w, 0.f);
    }
    *(float4*)&sgrp[grp][lane32 * 4] = csum;
    __syncthreads();
    if (tid < 128) {
        float ssum = 0.f;
#pragma unroll
        for (int j = 0; j < 16; ++j) ssum += sgrp[j][tid];
        partial[(size_t)(b * 2 + half) * 128 + tid] = ssum;
    }
}

// ---------------- fc: combine partials -> mean -> out = mean @ fw + fb ------
__global__ __launch_bounds__(128) void k_fc(const float* __restrict__ partial,
        const float* __restrict__ fw, const float* __restrict__ fb,
        float* __restrict__ out) {
    __shared__ float sm[HID];
    int b = blockIdx.x, f = threadIdx.x;
    float acc = partial[(size_t)(b * 2) * 128 + f] + partial[(size_t)(b * 2 + 1) * 128 + f];
    sm[f] = acc * (1.0f / RR);
    __syncthreads();
    if (f < NOUT) {
        float s = fb[f];
#pragma unroll
        for (int c = 0; c < HID; ++c) s += sm[c] * fw[c * NOUT + f];
        out[b * NOUT + f] = s;
    }
}

extern "C" void kernel_launch(void* const* d_in, const int* in_sizes, int n_in,
                              void* d_out, int out_size, void* d_ws, size_t ws_size,
                              hipStream_t stream) {
    const float* x   = (const float*)d_in[0];
    const int*   ei  = (const int*)d_in[1];
    const float* c1w = (const float*)d_in[2];
    const float* c1b = (const float*)d_in[3];
    const float* c2w = (const float*)d_in[4];
    const float* c2b = (const float*)d_in[5];
    const float* g1w = (const float*)d_in[6];
    const float* g1b = (const float*)d_in[7];
    const float* g2w = (const float*)d_in[8];
    const float* g2b = (const float*)d_in[9];
    const float* fw  = (const float*)d_in[10];
    const float* fb  = (const float*)d_in[11];
    float* out = (float*)d_out;
    int E  = in_sizes[1] / 2;   // total edges (1048576)
    int es = E / BB;            // edges per sample graph (8192)

    char* ws = (char*)d_ws;
    float*          nodes   = (float*)(ws);                         // 8 MB [N,32] f32
    unsigned short* bufA16  = (unsigned short*)(ws + (8u  << 20));  // 16 MB [N,128] bf16
    int*   rptr    = (int*)  (ws + (24u << 20));                    // [513]
    float* dis     = (float*)(ws + (24u << 20) + 4096);             // [512]
    int*   adj     = (int*)  (ws + (24u << 20) + 8192);             // 32 KB [es]
    unsigned short* w1t = (unsigned short*)(ws + (24u << 20) + 49152);  // 8 KB
    unsigned short* w2t = (unsigned short*)(ws + (24u << 20) + 65536);  // 32 KB
    float* partial = (float*)(ws + (25u << 20));                    // 128 KB [256,128]

    // convs (blocks 0..1023) + CSR (block 1024) + weight transpose (block 1025)
    k_convs<<<1026, 512, 0, stream>>>(x, c1w, c1b, c2w, c2b, nodes,
                                      ei, E, es, rptr, dis, adj,
                                      g1w, g2w, w1t, w2t);

    // layer 1: LDS-staged gather + MFMA lin1 -> bf16
    k_gl1<<<256, 512, 0, stream>>>(rptr, adj, dis, nodes, w1t, g1b, bufA16);

    // layer 2: staged lin2(MFMA, in-LDS) + gather + bias + relu + mean partial
    k_l2<<<256, 512, 0, stream>>>(rptr, adj, dis, bufA16, w2t, g2b, partial);

    // fc
    k_fc<<<BB, 128, 0, stream>>>(partial, fw, fb, out);
}